// Round 1
// baseline (2851.798 us; speedup 1.0000x reference)
//
#include <hip/hip_runtime.h>
#include <stdint.h>

#define DEVFN static __device__ __forceinline__

// ---------------- Threefry-2x32 (20 rounds), exactly as JAX ----------------
DEVFN uint32_t rotl32(uint32_t v, int d) { return (v << d) | (v >> (32 - d)); }

DEVFN void tf2x32(uint32_t k0, uint32_t k1, uint32_t x0, uint32_t x1,
                  uint32_t& o0, uint32_t& o1) {
  uint32_t k2 = k0 ^ k1 ^ 0x1BD11BDAu;
  x0 += k0; x1 += k1;
  x0 += x1; x1 = rotl32(x1, 13); x1 ^= x0;
  x0 += x1; x1 = rotl32(x1, 15); x1 ^= x0;
  x0 += x1; x1 = rotl32(x1, 26); x1 ^= x0;
  x0 += x1; x1 = rotl32(x1, 6);  x1 ^= x0;
  x0 += k1; x1 += k2 + 1u;
  x0 += x1; x1 = rotl32(x1, 17); x1 ^= x0;
  x0 += x1; x1 = rotl32(x1, 29); x1 ^= x0;
  x0 += x1; x1 = rotl32(x1, 16); x1 ^= x0;
  x0 += x1; x1 = rotl32(x1, 24); x1 ^= x0;
  x0 += k2; x1 += k0 + 2u;
  x0 += x1; x1 = rotl32(x1, 13); x1 ^= x0;
  x0 += x1; x1 = rotl32(x1, 15); x1 ^= x0;
  x0 += x1; x1 = rotl32(x1, 26); x1 ^= x0;
  x0 += x1; x1 = rotl32(x1, 6);  x1 ^= x0;
  x0 += k0; x1 += k1 + 3u;
  x0 += x1; x1 = rotl32(x1, 17); x1 ^= x0;
  x0 += x1; x1 = rotl32(x1, 29); x1 ^= x0;
  x0 += x1; x1 = rotl32(x1, 16); x1 ^= x0;
  x0 += x1; x1 = rotl32(x1, 24); x1 ^= x0;
  x0 += k1; x1 += k2 + 4u;
  x0 += x1; x1 = rotl32(x1, 13); x1 ^= x0;
  x0 += x1; x1 = rotl32(x1, 15); x1 ^= x0;
  x0 += x1; x1 = rotl32(x1, 26); x1 ^= x0;
  x0 += x1; x1 = rotl32(x1, 6);  x1 ^= x0;
  x0 += k2; x1 += k0 + 5u;
  o0 = x0; o1 = x1;
}

// ---------------- XLA/CHLO f32 erf_inv (Giles), w = -log1p(-x^2) -----------
DEVFN float erfinv_f32(float x) {
#pragma clang fp contract(off)
  float w = -log1pf(-(x * x));
  float p;
  if (w < 5.0f) {
    w = w - 2.5f;
    p = 2.81022636e-08f;
    p = 3.43273939e-07f + p * w;
    p = -3.5233877e-06f + p * w;
    p = -4.39150654e-06f + p * w;
    p = 0.00021858087f + p * w;
    p = -0.00125372503f + p * w;
    p = -0.00417768164f + p * w;
    p = 0.246640727f + p * w;
    p = 1.50140941f + p * w;
  } else {
    w = __fsqrt_rn(w) - 3.0f;
    p = -0.000200214257f;
    p = 0.000100950558f + p * w;
    p = 0.00134934322f + p * w;
    p = -0.00367342844f + p * w;
    p = 0.00573950773f + p * w;
    p = -0.0076224613f + p * w;
    p = 0.00943887047f + p * w;
    p = 1.00167406f + p * w;
    p = 2.83297682f + p * w;
  }
  return p * x;
}

// jax.nn.softplus(x) = logaddexp(x,0) = max(x,0) + log1p(exp(-|x|))
DEVFN float softplus_ref(float v) {
#pragma clang fp contract(off)
  return fmaxf(v, 0.0f) + log1pf(expf(-fabsf(v)));
}

// ---------------- fp32 GEMM: C = act(A[M,K] @ W[K,N] + bias) ----------------
// BM=BN=128, BK=16, 256 threads, 8x8 per thread. M,N,K multiples of tile dims.
// ACT: 1 = relu -> C0[M,N];  3 = 1e-6+softplus, split columns at `split`
//      (cols < split -> C0 row-stride split, else C1 row-stride split)
template <int ACT>
__global__ __launch_bounds__(256) void gemm128(
    const float* __restrict__ A, const float* __restrict__ W,
    const float* __restrict__ bias, float* __restrict__ C0,
    float* __restrict__ C1, int M, int N, int K, int split) {
  __shared__ float As[16][132];
  __shared__ float Bs[16][132];
  const int tid = threadIdx.x;
  const int m0 = blockIdx.y * 128;
  const int n0 = blockIdx.x * 128;
  const int tx = tid & 15;   // col group
  const int ty = tid >> 4;   // row group
  float acc[8][8];
#pragma unroll
  for (int i = 0; i < 8; i++)
#pragma unroll
    for (int j = 0; j < 8; j++) acc[i][j] = 0.0f;

  const int arow = tid >> 2;           // 0..63 (+64)
  const int acol = (tid & 3) << 2;     // 0,4,8,12
  const int brow = tid >> 5;           // 0..7 (+8)
  const int bcol = (tid & 31) << 2;    // 0..124

  for (int k0 = 0; k0 < K; k0 += 16) {
#pragma unroll
    for (int h = 0; h < 2; h++) {
      int r = arow + h * 64;
      float4 a = *(const float4*)(A + (size_t)(m0 + r) * K + k0 + acol);
      As[acol + 0][r] = a.x; As[acol + 1][r] = a.y;
      As[acol + 2][r] = a.z; As[acol + 3][r] = a.w;
    }
#pragma unroll
    for (int h = 0; h < 2; h++) {
      int r = brow + h * 8;
      *(float4*)&Bs[r][bcol] =
          *(const float4*)(W + (size_t)(k0 + r) * N + n0 + bcol);
    }
    __syncthreads();
#pragma unroll
    for (int k = 0; k < 16; k++) {
      float af[8], bf[8];
      *(float4*)&af[0] = *(const float4*)&As[k][ty * 8];
      *(float4*)&af[4] = *(const float4*)&As[k][ty * 8 + 4];
      *(float4*)&bf[0] = *(const float4*)&Bs[k][tx * 8];
      *(float4*)&bf[4] = *(const float4*)&Bs[k][tx * 8 + 4];
#pragma unroll
      for (int i = 0; i < 8; i++)
#pragma unroll
        for (int j = 0; j < 8; j++) acc[i][j] = fmaf(af[i], bf[j], acc[i][j]);
    }
    __syncthreads();
  }

#pragma unroll
  for (int i = 0; i < 8; i++) {
    size_t row = (size_t)(m0 + ty * 8 + i);
#pragma unroll
    for (int j = 0; j < 8; j++) {
      int col = n0 + tx * 8 + j;
      float v = acc[i][j] + bias[col];
      if (ACT == 1) {
        v = fmaxf(v, 0.0f);
        C0[row * (size_t)N + col] = v;
      } else if (ACT == 3) {
        v = 1e-6f + softplus_ref(v);
        if (col < split) C0[row * (size_t)split + col] = v;
        else             C1[row * (size_t)split + (col - split)] = v;
      } else {
        C0[row * (size_t)N + col] = v;
      }
    }
  }
}

// ---------------- fused fc41 + fc42 (N=64 each): 1e-6+softplus --------------
// BM=64, 128 output cols (64 from W1, 64 from W2), 256 threads, 8x4/thread
__global__ __launch_bounds__(256) void dual64(
    const float* __restrict__ A, const float* __restrict__ W1,
    const float* __restrict__ b1, const float* __restrict__ W2,
    const float* __restrict__ b2, float* __restrict__ O1,
    float* __restrict__ O2, int K) {
  __shared__ float As[16][68];
  __shared__ float Bs[16][132];
  const int tid = threadIdx.x;
  const int m0 = blockIdx.x * 64;
  const int tx = tid & 31;  // col group: col0 = tx*4
  const int ty = tid >> 5;  // row group: row0 = ty*8
  float acc[8][4];
#pragma unroll
  for (int i = 0; i < 8; i++)
#pragma unroll
    for (int j = 0; j < 4; j++) acc[i][j] = 0.0f;

  const int arow = tid >> 2;
  const int acol = (tid & 3) << 2;
  const int brow = tid >> 5;
  const int bcol = (tid & 31) << 2;

  for (int k0 = 0; k0 < K; k0 += 16) {
    {
      float4 a = *(const float4*)(A + (size_t)(m0 + arow) * K + k0 + acol);
      As[acol + 0][arow] = a.x; As[acol + 1][arow] = a.y;
      As[acol + 2][arow] = a.z; As[acol + 3][arow] = a.w;
    }
#pragma unroll
    for (int h = 0; h < 2; h++) {
      int r = brow + h * 8;
      const float* src = (bcol < 64) ? (W1 + (size_t)(k0 + r) * 64 + bcol)
                                     : (W2 + (size_t)(k0 + r) * 64 + (bcol - 64));
      *(float4*)&Bs[r][bcol] = *(const float4*)src;
    }
    __syncthreads();
#pragma unroll
    for (int k = 0; k < 16; k++) {
      float af[8], bf[4];
      *(float4*)&af[0] = *(const float4*)&As[k][ty * 8];
      *(float4*)&af[4] = *(const float4*)&As[k][ty * 8 + 4];
      *(float4*)&bf[0] = *(const float4*)&Bs[k][tx * 4];
#pragma unroll
      for (int i = 0; i < 8; i++)
#pragma unroll
        for (int j = 0; j < 4; j++) acc[i][j] = fmaf(af[i], bf[j], acc[i][j]);
    }
    __syncthreads();
  }

#pragma unroll
  for (int i = 0; i < 8; i++) {
    size_t row = (size_t)(m0 + ty * 8 + i);
#pragma unroll
    for (int j = 0; j < 4; j++) {
      int col = tx * 4 + j;  // 0..127
      float bb = (col < 64) ? b1[col] : b2[col - 64];
      float v = 1e-6f + softplus_ref(acc[i][j] + bb);
      if (col < 64) O1[row * 64 + col] = v;
      else          O2[row * 64 + (col - 64)] = v;
    }
  }
}

// ---------------- Marsaglia-Tsang sampler, JAX partitionable threefry -------
// eps bits[i] = o0 of TF(k1,(0,i)); u bits[i] = o0 of TF(k2,(0,i)),
// i = k*524288 + tid, k = round. k1/k2 from foldlike split of key(42).
__global__ __launch_bounds__(256) void gamma_sampler(
    const float* __restrict__ la, const float* __restrict__ lb,
    float* __restrict__ z) {
#pragma clang fp contract(off)
  const uint32_t i = blockIdx.x * 256u + threadIdx.x;
  uint32_t k1a, k1b, k2a, k2b;
  tf2x32(0u, 42u, 0u, 0u, k1a, k1b);  // k1 = split(key)[0]
  tf2x32(0u, 42u, 0u, 1u, k2a, k2b);  // k2 = split(key)[1]

  const float LO = __uint_as_float(0xBF7FFFFFu);      // nextafter(-1,0)
  const float SQRT2 = __uint_as_float(0x3FB504F3u);   // f32(sqrt(2))
  const float USCALE = 1.0f - 1e-7f;                  // folds to 0x3F7FFFFE

  const float al = la[i];
  const float be = lb[i];
  const float d = (al + 1.0f) - 0.33333334f;          // f32(1.0/3.0)
  const float c = 1.0f / __fsqrt_rn(9.0f * d);

  float es = 0.0f, us = 0.0f;
  bool done = false;
  for (int k = 0; k < 24; k++) {
    if (__all(done)) break;
    if (!done) {
      uint32_t n = (uint32_t)k * 524288u + i;
      uint32_t o0, o1, p0, p1;
      tf2x32(k1a, k1b, 0u, n, o0, o1);
      tf2x32(k2a, k2b, 0u, n, p0, p1);
      // normal: uniform(lo=nextafter(-1,0), hi=1) -> sqrt2*erfinv
      float f = __uint_as_float((o0 >> 9) | 0x3F800000u) - 1.0f;
      float un = f * 2.0f + LO;   // (hi-lo) rounds to exactly 2.0f
      un = fmaxf(LO, un);
      float e = SQRT2 * erfinv_f32(un);
      // uniform(1e-7, 1.0)
      float g = __uint_as_float((p0 >> 9) | 0x3F800000u) - 1.0f;
      float u = g * USCALE + 1e-7f;
      u = fmaxf(1e-7f, u);
      if (k == 0) { es = e; us = u; }  // argmax fallback = round 0
      float v = 1.0f + c * e;
      if (v > 0.0f) {
        float v3 = (v * v) * v;
        float e2 = e * e;
        bool acc = false;
        float sq = 1.0f - (0.0331f * e2) * e2;   // 0.0331*(e*e)*(e*e)
        if (u < sq) acc = true;
        else {
          float rhs = (0.5f * e) * e + d * ((1.0f - v3) + logf(v3));
          if (logf(u) < rhs) acc = true;
        }
        if (acc) { es = e; us = u; done = true; }
      }
    }
  }
  float vv = 1.0f + c * es;
  float vs = (vv * vv) * vv;
  float t = logf(d * vs + 1e-6f) + logf(us + 1e-6f) / (al + 1e-6f);
  z[i] = expf(t) / (be + 1e-6f);
}

// ---------------------------------------------------------------------------
extern "C" void kernel_launch(void* const* d_in, const int* in_sizes, int n_in,
                              void* d_out, int out_size, void* d_ws,
                              size_t ws_size, hipStream_t stream) {
  const float* x   = (const float*)d_in[0];
  const float* w1  = (const float*)d_in[1];  const float* b1  = (const float*)d_in[2];
  const float* w2  = (const float*)d_in[3];  const float* b2  = (const float*)d_in[4];
  const float* w3  = (const float*)d_in[5];  const float* b3  = (const float*)d_in[6];
  const float* w41 = (const float*)d_in[7];  const float* b41 = (const float*)d_in[8];
  const float* w42 = (const float*)d_in[9];  const float* b42 = (const float*)d_in[10];
  const float* w4  = (const float*)d_in[11]; const float* b4  = (const float*)d_in[12];
  const float* w5  = (const float*)d_in[13]; const float* b5  = (const float*)d_in[14];
  const float* w6  = (const float*)d_in[15]; const float* b6  = (const float*)d_in[16];
  const float* w7  = (const float*)d_in[17]; const float* b7  = (const float*)d_in[18];
  float* out = (float*)d_out;
  float* ws  = (float*)d_ws;

  // output layout (floats): recon_al | recon_be | logalpha | logbeta | z
  float* recon_a = out;
  float* recon_b = out + 16777216;   // 8192*2048
  float* la      = out + 33554432;
  float* lb      = out + 34078720;
  float* zz      = out + 34603008;

  // workspace layout (floats), peak 128 MiB with reuse
  float* h1 = ws;               // 8192*1024
  float* h2 = ws + 8388608;     // 8192*1024
  float* h3 = ws + 16777216;    // 8192*2048
  float* h4 = ws + 16777216;    // reuse h3 slot (h3 dead after dual64)
  float* h5 = ws;               // reuse h1 slot
  float* h6 = ws + 8388608;     // reuse h2 slot

  dim3 blk(256);
  // encoder
  gemm128<1><<<dim3(8, 64),  blk, 0, stream>>>(x,  w1, b1, h1, nullptr, 8192, 1024, 2048, 0);
  gemm128<1><<<dim3(8, 64),  blk, 0, stream>>>(h1, w2, b2, h2, nullptr, 8192, 1024, 1024, 0);
  gemm128<1><<<dim3(16, 64), blk, 0, stream>>>(h2, w3, b3, h3, nullptr, 8192, 2048, 1024, 0);
  dual64<<<dim3(128), blk, 0, stream>>>(h3, w41, b41, w42, b42, la, lb, 2048);
  // reparameterize
  gamma_sampler<<<dim3(2048), blk, 0, stream>>>(la, lb, zz);
  // decoder
  gemm128<1><<<dim3(16, 64), blk, 0, stream>>>(zz, w4, b4, h4, nullptr, 8192, 2048, 64, 0);
  gemm128<1><<<dim3(8, 64),  blk, 0, stream>>>(h4, w5, b5, h5, nullptr, 8192, 1024, 2048, 0);
  gemm128<1><<<dim3(8, 64),  blk, 0, stream>>>(h5, w6, b6, h6, nullptr, 8192, 1024, 1024, 0);
  gemm128<3><<<dim3(32, 64), blk, 0, stream>>>(h6, w7, b7, recon_a, recon_b, 8192, 4096, 1024, 2048);
  (void)in_sizes; (void)n_in; (void)out_size; (void)ws_size;
}

// Round 2
// 1843.488 us; speedup vs baseline: 1.5470x; 1.5470x over previous
//
#include <hip/hip_runtime.h>
#include <stdint.h>

#define DEVFN static __device__ __forceinline__

typedef __attribute__((ext_vector_type(8))) short short8;
typedef __attribute__((ext_vector_type(4))) float floatx4;

// ---------------- Threefry-2x32 (20 rounds), exactly as JAX ----------------
DEVFN uint32_t rotl32(uint32_t v, int d) { return (v << d) | (v >> (32 - d)); }

DEVFN void tf2x32(uint32_t k0, uint32_t k1, uint32_t x0, uint32_t x1,
                  uint32_t& o0, uint32_t& o1) {
  uint32_t k2 = k0 ^ k1 ^ 0x1BD11BDAu;
  x0 += k0; x1 += k1;
  x0 += x1; x1 = rotl32(x1, 13); x1 ^= x0;
  x0 += x1; x1 = rotl32(x1, 15); x1 ^= x0;
  x0 += x1; x1 = rotl32(x1, 26); x1 ^= x0;
  x0 += x1; x1 = rotl32(x1, 6);  x1 ^= x0;
  x0 += k1; x1 += k2 + 1u;
  x0 += x1; x1 = rotl32(x1, 17); x1 ^= x0;
  x0 += x1; x1 = rotl32(x1, 29); x1 ^= x0;
  x0 += x1; x1 = rotl32(x1, 16); x1 ^= x0;
  x0 += x1; x1 = rotl32(x1, 24); x1 ^= x0;
  x0 += k2; x1 += k0 + 2u;
  x0 += x1; x1 = rotl32(x1, 13); x1 ^= x0;
  x0 += x1; x1 = rotl32(x1, 15); x1 ^= x0;
  x0 += x1; x1 = rotl32(x1, 26); x1 ^= x0;
  x0 += x1; x1 = rotl32(x1, 6);  x1 ^= x0;
  x0 += k0; x1 += k1 + 3u;
  x0 += x1; x1 = rotl32(x1, 17); x1 ^= x0;
  x0 += x1; x1 = rotl32(x1, 29); x1 ^= x0;
  x0 += x1; x1 = rotl32(x1, 16); x1 ^= x0;
  x0 += x1; x1 = rotl32(x1, 24); x1 ^= x0;
  x0 += k1; x1 += k2 + 4u;
  x0 += x1; x1 = rotl32(x1, 13); x1 ^= x0;
  x0 += x1; x1 = rotl32(x1, 15); x1 ^= x0;
  x0 += x1; x1 = rotl32(x1, 26); x1 ^= x0;
  x0 += x1; x1 = rotl32(x1, 6);  x1 ^= x0;
  x0 += k2; x1 += k0 + 5u;
  o0 = x0; o1 = x1;
}

// ---------------- XLA/CHLO f32 erf_inv (Giles), w = -log1p(-x^2) -----------
DEVFN float erfinv_f32(float x) {
#pragma clang fp contract(off)
  float w = -log1pf(-(x * x));
  float p;
  if (w < 5.0f) {
    w = w - 2.5f;
    p = 2.81022636e-08f;
    p = 3.43273939e-07f + p * w;
    p = -3.5233877e-06f + p * w;
    p = -4.39150654e-06f + p * w;
    p = 0.00021858087f + p * w;
    p = -0.00125372503f + p * w;
    p = -0.00417768164f + p * w;
    p = 0.246640727f + p * w;
    p = 1.50140941f + p * w;
  } else {
    w = __fsqrt_rn(w) - 3.0f;
    p = -0.000200214257f;
    p = 0.000100950558f + p * w;
    p = 0.00134934322f + p * w;
    p = -0.00367342844f + p * w;
    p = 0.00573950773f + p * w;
    p = -0.0076224613f + p * w;
    p = 0.00943887047f + p * w;
    p = 1.00167406f + p * w;
    p = 2.83297682f + p * w;
  }
  return p * x;
}

// jax.nn.softplus(x) = logaddexp(x,0) = max(x,0) + log1p(exp(-|x|))
DEVFN float softplus_ref(float v) {
#pragma clang fp contract(off)
  return fmaxf(v, 0.0f) + log1pf(expf(-fabsf(v)));
}

// fp32 -> bf16 RNE
DEVFN ushort f2bf(float f) {
  uint32_t u = __float_as_uint(f);
  uint32_t r = (u + 0x7FFFu + ((u >> 16) & 1u)) >> 16;
  return (ushort)r;
}

// async global->LDS, 16 B per lane; lds must be wave-uniform base
DEVFN void gl2lds16(const void* g, void* l) {
  __builtin_amdgcn_global_load_lds(
      (const __attribute__((address_space(1))) void*)g,
      (__attribute__((address_space(3))) void*)l, 16, 0, 0);
}

// ---------------- fp32 GEMM: C = act(A[M,K] @ W[K,N] + bias) ----------------
// BM=BN=128, BK=16, 256 threads, 8x8 per thread. (encoder: must stay fp32 —
// logalpha feeds discrete accept/reject; bf16 noise would flip accepts)
template <int ACT>
__global__ __launch_bounds__(256) void gemm128(
    const float* __restrict__ A, const float* __restrict__ W,
    const float* __restrict__ bias, float* __restrict__ C0,
    float* __restrict__ C1, int M, int N, int K, int split) {
  __shared__ float As[16][132];
  __shared__ float Bs[16][132];
  const int tid = threadIdx.x;
  const int m0 = blockIdx.y * 128;
  const int n0 = blockIdx.x * 128;
  const int tx = tid & 15;
  const int ty = tid >> 4;
  float acc[8][8];
#pragma unroll
  for (int i = 0; i < 8; i++)
#pragma unroll
    for (int j = 0; j < 8; j++) acc[i][j] = 0.0f;

  const int arow = tid >> 2;
  const int acol = (tid & 3) << 2;
  const int brow = tid >> 5;
  const int bcol = (tid & 31) << 2;

  for (int k0 = 0; k0 < K; k0 += 16) {
#pragma unroll
    for (int h = 0; h < 2; h++) {
      int r = arow + h * 64;
      float4 a = *(const float4*)(A + (size_t)(m0 + r) * K + k0 + acol);
      As[acol + 0][r] = a.x; As[acol + 1][r] = a.y;
      As[acol + 2][r] = a.z; As[acol + 3][r] = a.w;
    }
#pragma unroll
    for (int h = 0; h < 2; h++) {
      int r = brow + h * 8;
      *(float4*)&Bs[r][bcol] =
          *(const float4*)(W + (size_t)(k0 + r) * N + n0 + bcol);
    }
    __syncthreads();
#pragma unroll
    for (int k = 0; k < 16; k++) {
      float af[8], bf[8];
      *(float4*)&af[0] = *(const float4*)&As[k][ty * 8];
      *(float4*)&af[4] = *(const float4*)&As[k][ty * 8 + 4];
      *(float4*)&bf[0] = *(const float4*)&Bs[k][tx * 8];
      *(float4*)&bf[4] = *(const float4*)&Bs[k][tx * 8 + 4];
#pragma unroll
      for (int i = 0; i < 8; i++)
#pragma unroll
        for (int j = 0; j < 8; j++) acc[i][j] = fmaf(af[i], bf[j], acc[i][j]);
    }
    __syncthreads();
  }

#pragma unroll
  for (int i = 0; i < 8; i++) {
    size_t row = (size_t)(m0 + ty * 8 + i);
#pragma unroll
    for (int j = 0; j < 8; j++) {
      int col = n0 + tx * 8 + j;
      float v = acc[i][j] + bias[col];
      if (ACT == 1) {
        v = fmaxf(v, 0.0f);
        C0[row * (size_t)N + col] = v;
      } else if (ACT == 3) {
        v = 1e-6f + softplus_ref(v);
        if (col < split) C0[row * (size_t)split + col] = v;
        else             C1[row * (size_t)split + (col - split)] = v;
      } else {
        C0[row * (size_t)N + col] = v;
      }
    }
  }
}

// ---------------- fused fc41 + fc42 (N=64 each): 1e-6+softplus --------------
__global__ __launch_bounds__(256) void dual64(
    const float* __restrict__ A, const float* __restrict__ W1,
    const float* __restrict__ b1, const float* __restrict__ W2,
    const float* __restrict__ b2, float* __restrict__ O1,
    float* __restrict__ O2, int K) {
  __shared__ float As[16][68];
  __shared__ float Bs[16][132];
  const int tid = threadIdx.x;
  const int m0 = blockIdx.x * 64;
  const int tx = tid & 31;
  const int ty = tid >> 5;
  float acc[8][4];
#pragma unroll
  for (int i = 0; i < 8; i++)
#pragma unroll
    for (int j = 0; j < 4; j++) acc[i][j] = 0.0f;

  const int arow = tid >> 2;
  const int acol = (tid & 3) << 2;
  const int brow = tid >> 5;
  const int bcol = (tid & 31) << 2;

  for (int k0 = 0; k0 < K; k0 += 16) {
    {
      float4 a = *(const float4*)(A + (size_t)(m0 + arow) * K + k0 + acol);
      As[acol + 0][arow] = a.x; As[acol + 1][arow] = a.y;
      As[acol + 2][arow] = a.z; As[acol + 3][arow] = a.w;
    }
#pragma unroll
    for (int h = 0; h < 2; h++) {
      int r = brow + h * 8;
      const float* src = (bcol < 64) ? (W1 + (size_t)(k0 + r) * 64 + bcol)
                                     : (W2 + (size_t)(k0 + r) * 64 + (bcol - 64));
      *(float4*)&Bs[r][bcol] = *(const float4*)src;
    }
    __syncthreads();
#pragma unroll
    for (int k = 0; k < 16; k++) {
      float af[8], bf[4];
      *(float4*)&af[0] = *(const float4*)&As[k][ty * 8];
      *(float4*)&af[4] = *(const float4*)&As[k][ty * 8 + 4];
      *(float4*)&bf[0] = *(const float4*)&Bs[k][tx * 4];
#pragma unroll
      for (int i = 0; i < 8; i++)
#pragma unroll
        for (int j = 0; j < 4; j++) acc[i][j] = fmaf(af[i], bf[j], acc[i][j]);
    }
    __syncthreads();
  }

#pragma unroll
  for (int i = 0; i < 8; i++) {
    size_t row = (size_t)(m0 + ty * 8 + i);
#pragma unroll
    for (int j = 0; j < 4; j++) {
      int col = tx * 4 + j;
      float bb = (col < 64) ? b1[col] : b2[col - 64];
      float v = 1e-6f + softplus_ref(acc[i][j] + bb);
      if (col < 64) O1[row * 64 + col] = v;
      else          O2[row * 64 + (col - 64)] = v;
    }
  }
}

// ---------------- Marsaglia-Tsang sampler, JAX partitionable threefry -------
__global__ __launch_bounds__(256) void gamma_sampler(
    const float* __restrict__ la, const float* __restrict__ lb,
    float* __restrict__ z, ushort* __restrict__ zb) {
#pragma clang fp contract(off)
  const uint32_t i = blockIdx.x * 256u + threadIdx.x;
  uint32_t k1a, k1b, k2a, k2b;
  tf2x32(0u, 42u, 0u, 0u, k1a, k1b);
  tf2x32(0u, 42u, 0u, 1u, k2a, k2b);

  const float LO = __uint_as_float(0xBF7FFFFFu);
  const float SQRT2 = __uint_as_float(0x3FB504F3u);
  const float USCALE = 1.0f - 1e-7f;

  const float al = la[i];
  const float be = lb[i];
  const float d = (al + 1.0f) - 0.33333334f;
  const float c = 1.0f / __fsqrt_rn(9.0f * d);

  float es = 0.0f, us = 0.0f;
  bool done = false;
  for (int k = 0; k < 24; k++) {
    if (__all(done)) break;
    if (!done) {
      uint32_t n = (uint32_t)k * 524288u + i;
      uint32_t o0, o1, p0, p1;
      tf2x32(k1a, k1b, 0u, n, o0, o1);
      tf2x32(k2a, k2b, 0u, n, p0, p1);
      float f = __uint_as_float((o0 >> 9) | 0x3F800000u) - 1.0f;
      float un = f * 2.0f + LO;
      un = fmaxf(LO, un);
      float e = SQRT2 * erfinv_f32(un);
      float g = __uint_as_float((p0 >> 9) | 0x3F800000u) - 1.0f;
      float u = g * USCALE + 1e-7f;
      u = fmaxf(1e-7f, u);
      if (k == 0) { es = e; us = u; }
      float v = 1.0f + c * e;
      if (v > 0.0f) {
        float v3 = (v * v) * v;
        float e2 = e * e;
        bool acc = false;
        float sq = 1.0f - (0.0331f * e2) * e2;
        if (u < sq) acc = true;
        else {
          float rhs = (0.5f * e) * e + d * ((1.0f - v3) + logf(v3));
          if (logf(u) < rhs) acc = true;
        }
        if (acc) { es = e; us = u; done = true; }
      }
    }
  }
  float vv = 1.0f + c * es;
  float vs = (vv * vv) * vv;
  float t = logf(d * vs + 1e-6f) + logf(us + 1e-6f) / (al + 1e-6f);
  float zv = expf(t) / (be + 1e-6f);
  z[i] = zv;
  zb[i] = f2bf(zv);
}

// ---------------- transpose + fp32->bf16: out[c][r] = bf16(in[r][c]) --------
__global__ __launch_bounds__(256) void transpose_bf16(
    const float* __restrict__ in, ushort* __restrict__ out, int R, int C) {
  __shared__ float tile[32][33];
  const int c0 = blockIdx.x * 32, r0 = blockIdx.y * 32;
  const int tx = threadIdx.x & 31, ty = threadIdx.x >> 5;
#pragma unroll
  for (int i = ty; i < 32; i += 8)
    tile[i][tx] = in[(size_t)(r0 + i) * C + c0 + tx];
  __syncthreads();
#pragma unroll
  for (int i = ty; i < 32; i += 8)
    out[(size_t)(c0 + i) * R + r0 + tx] = f2bf(tile[tx][i]);
}

// ---------------- bf16 MFMA GEMM (m97-style): C = act(A @ Bt^T + bias) ------
// A [M,K] bf16 row-major, Bt [N,K] bf16 row-major (i.e. W^T).
// 128x128 tile, BK=32, 256 thr = 4 waves in 2x2, 16x16x32 MFMA, 4x4/wave.
// ACT 0: relu -> bf16 C0b[M,N];  ACT 3: 1e-6+softplus split -> fp32 C0f/C1f
template <int ACT>
__global__ __launch_bounds__(256) void gemm_bf16(
    const ushort* __restrict__ A, const ushort* __restrict__ Bt,
    const float* __restrict__ bias, ushort* __restrict__ C0b,
    float* __restrict__ C0f, float* __restrict__ C1f,
    int M, int N, int K, int split) {
  __shared__ ushort As[128 * 32];
  __shared__ ushort Bs[128 * 32];
  const int tid = threadIdx.x;
  const int wave = tid >> 6, lane = tid & 63;
  const int m0 = blockIdx.y * 128, n0 = blockIdx.x * 128;
  const int lrow = lane & 15, lq = lane >> 4;
  const int wm = wave & 1, wn = wave >> 1;
  const int srow = lane >> 2;       // 16 rows per wave-call
  const int scol = (lane & 3) * 8;  // k offset (elements)

  floatx4 acc[4][4];
#pragma unroll
  for (int i = 0; i < 4; i++)
#pragma unroll
    for (int j = 0; j < 4; j++) acc[i][j] = (floatx4){0.f, 0.f, 0.f, 0.f};

  for (int k0 = 0; k0 < K; k0 += 32) {
#pragma unroll
    for (int h = 0; h < 2; h++) {
      int r0 = wave * 32 + h * 16;
      gl2lds16(A + (size_t)(m0 + r0 + srow) * K + k0 + scol, &As[r0 * 32]);
      gl2lds16(Bt + (size_t)(n0 + r0 + srow) * K + k0 + scol, &Bs[r0 * 32]);
    }
    __syncthreads();   // compiler drains vmcnt before s_barrier
    short8 a[4], b[4];
#pragma unroll
    for (int i = 0; i < 4; i++) {
      a[i] = *(const short8*)&As[(wm * 64 + i * 16 + lrow) * 32 + lq * 8];
      b[i] = *(const short8*)&Bs[(wn * 64 + i * 16 + lrow) * 32 + lq * 8];
    }
#pragma unroll
    for (int i = 0; i < 4; i++)
#pragma unroll
      for (int j = 0; j < 4; j++)
        acc[i][j] = __builtin_amdgcn_mfma_f32_16x16x32_bf16(a[i], b[j],
                                                            acc[i][j], 0, 0, 0);
    __syncthreads();
  }

  // C/D layout: col = lane&15, row = (lane>>4)*4 + reg  [measured m89/m91]
#pragma unroll
  for (int i = 0; i < 4; i++) {
#pragma unroll
    for (int j = 0; j < 4; j++) {
      int colg = n0 + wn * 64 + j * 16 + lrow;
      float bb = bias[colg];
#pragma unroll
      for (int r = 0; r < 4; r++) {
        int rowg = m0 + wm * 64 + i * 16 + lq * 4 + r;
        float v = acc[i][j][r] + bb;
        if (ACT == 0) {
          v = fmaxf(v, 0.0f);
          C0b[(size_t)rowg * N + colg] = f2bf(v);
        } else {
          v = 1e-6f + softplus_ref(v);
          if (colg < split) C0f[(size_t)rowg * split + colg] = v;
          else              C1f[(size_t)rowg * split + (colg - split)] = v;
        }
      }
    }
  }
}

// ---------------------------------------------------------------------------
extern "C" void kernel_launch(void* const* d_in, const int* in_sizes, int n_in,
                              void* d_out, int out_size, void* d_ws,
                              size_t ws_size, hipStream_t stream) {
  const float* x   = (const float*)d_in[0];
  const float* w1  = (const float*)d_in[1];  const float* b1  = (const float*)d_in[2];
  const float* w2  = (const float*)d_in[3];  const float* b2  = (const float*)d_in[4];
  const float* w3  = (const float*)d_in[5];  const float* b3  = (const float*)d_in[6];
  const float* w41 = (const float*)d_in[7];  const float* b41 = (const float*)d_in[8];
  const float* w42 = (const float*)d_in[9];  const float* b42 = (const float*)d_in[10];
  const float* w4  = (const float*)d_in[11]; const float* b4  = (const float*)d_in[12];
  const float* w5  = (const float*)d_in[13]; const float* b5  = (const float*)d_in[14];
  const float* w6  = (const float*)d_in[15]; const float* b6  = (const float*)d_in[16];
  const float* w7  = (const float*)d_in[17]; const float* b7  = (const float*)d_in[18];
  float* out = (float*)d_out;
  float* ws  = (float*)d_ws;
  ushort* wsu = (ushort*)d_ws;

  // output layout (floats): recon_al | recon_be | logalpha | logbeta | z
  float* recon_a = out;
  float* recon_b = out + 16777216;
  float* la      = out + 33554432;
  float* lb      = out + 34078720;
  float* zz      = out + 34603008;

  // encoder fp32 workspace (floats)
  float* h1 = ws;               // [0, 8388608)
  float* h2 = ws + 8388608;     // [8388608, 16777216)
  float* h3 = ws + 16777216;    // [16777216, 33554432)

  // decoder bf16 workspace (ushorts) — reuses encoder regions after death:
  // zb..w7T sit inside h1 (dead after fc2); h4b spans h1-tail+h2 (dead after
  // fc3); h5b inside h2; h6b inside h3 (dead after dual64).
  ushort* zb  = wsu;             // 8192*64
  ushort* w4T = wsu + 524288;    // [2048,64]
  ushort* w5T = wsu + 655360;    // [1024,2048]
  ushort* w6T = wsu + 2752512;   // [1024,1024]
  ushort* w7T = wsu + 3801088;   // [4096,1024]
  ushort* h4b = wsu + 7995392;   // [8192,2048]
  ushort* h5b = wsu + 24772608;  // [8192,1024]
  ushort* h6b = wsu + 33161216;  // [8192,1024]

  dim3 blk(256);
  // encoder (exact fp32 — feeds accept/reject decisions)
  gemm128<1><<<dim3(8, 64),  blk, 0, stream>>>(x,  w1, b1, h1, nullptr, 8192, 1024, 2048, 0);
  gemm128<1><<<dim3(8, 64),  blk, 0, stream>>>(h1, w2, b2, h2, nullptr, 8192, 1024, 1024, 0);
  // h1 dead: convert decoder weights (transposed, bf16)
  transpose_bf16<<<dim3(64, 2),   blk, 0, stream>>>(w4, w4T, 64,   2048);
  transpose_bf16<<<dim3(32, 64),  blk, 0, stream>>>(w5, w5T, 2048, 1024);
  transpose_bf16<<<dim3(32, 32),  blk, 0, stream>>>(w6, w6T, 1024, 1024);
  transpose_bf16<<<dim3(128, 32), blk, 0, stream>>>(w7, w7T, 1024, 4096);
  gemm128<1><<<dim3(16, 64), blk, 0, stream>>>(h2, w3, b3, h3, nullptr, 8192, 2048, 1024, 0);
  dual64<<<dim3(128), blk, 0, stream>>>(h3, w41, b41, w42, b42, la, lb, 2048);
  // reparameterize (exact fp32; also emits bf16 z)
  gamma_sampler<<<dim3(2048), blk, 0, stream>>>(la, lb, zz, zb);
  // decoder (bf16 MFMA)
  gemm_bf16<0><<<dim3(16, 64), blk, 0, stream>>>(zb,  w4T, b4, h4b, nullptr, nullptr, 8192, 2048, 64, 0);
  gemm_bf16<0><<<dim3(8, 64),  blk, 0, stream>>>(h4b, w5T, b5, h5b, nullptr, nullptr, 8192, 1024, 2048, 0);
  gemm_bf16<0><<<dim3(8, 64),  blk, 0, stream>>>(h5b, w6T, b6, h6b, nullptr, nullptr, 8192, 1024, 1024, 0);
  gemm_bf16<3><<<dim3(32, 64), blk, 0, stream>>>(h6b, w7T, b7, nullptr, recon_a, recon_b, 8192, 4096, 1024, 2048);
  (void)in_sizes; (void)n_in; (void)out_size; (void)ws_size;
}